// Round 16
// baseline (60.579 us; speedup 1.0000x reference)
//
#include <hip/hip_runtime.h>
#include <hip/hip_bf16.h>

// out[n,f] = weights[n] * ( x[n,:] . Wsum[f,:] + bsum[f] )
// Wsum = sum_e W[e], bsum = sum_e b[e]  (expert sum commutes with Linear).
// R15: FULL STREAMING DECOMPOSITION. Both GEMM operands pre-permuted into
// MFMA-fragment-major order (Bfrag: R6-proven; Afrag: new moe_xfrag pass with
// LDS-transpose) -> the GEMM is LDS-free, barrier-free, conversion-free: pure
// dense 16B/lane streams + MFMA + direct stores. Every kernel is copy-shaped
// (chip measured at 84% peak on pure streams vs 32% on the fused kernel).
// Fallback to the R6 fused kernel if ws_size < 34MB.

#define N_TOK 32768
#define DIM   512
#define NEXP  8

typedef __attribute__((ext_vector_type(8))) short  bf16x8;
typedef __attribute__((ext_vector_type(4))) float  f32x4;

__device__ __forceinline__ unsigned int pk2bf(float a, float b) {
    unsigned ua = __float_as_uint(a), ub = __float_as_uint(b);
    ua = (ua + 0x7FFFu + ((ua >> 16) & 1u)) >> 16;   // RNE to bf16
    ub = (ub + 0x7FFFu + ((ub >> 16) & 1u)) >> 16;
    return ua | (ub << 16);
}

// ---- one granule: 8 f32 -> 16B bf16, XOR-swizzled LDS write (proven pair) ----
__device__ __forceinline__ void stage_granule(const float* __restrict__ srcrow,
                                              unsigned char* __restrict__ dstrow,
                                              int g, int row) {
    float4 u0 = *(const float4*)(srcrow + g * 8);
    float4 u1 = *(const float4*)(srcrow + g * 8 + 4);
    const int sg = (g & ~7) | ((g ^ row) & 7);
    uint4 v;
    v.x = pk2bf(u0.x, u0.y); v.y = pk2bf(u0.z, u0.w);
    v.z = pk2bf(u1.x, u1.y); v.w = pk2bf(u1.z, u1.w);
    *(uint4*)(dstrow + sg * 16) = v;
}

// ---------------- prep: Bfrag (bf16, fragment-major) + bsum (f32) ---- (R6-proven) ----
__global__ __launch_bounds__(64) void moe_prep(const float* __restrict__ W,
                                               const float* __restrict__ b,
                                               unsigned short* __restrict__ Bfrag,
                                               float* __restrict__ bsum) {
    const int g = blockIdx.x * 64 + threadIdx.x;     // 0..32767
    const int f = g >> 6;
    const int q = g & 63;
    const float* src = W + (size_t)f * DIM + q * 8;
    float s0 = 0, s1 = 0, s2 = 0, s3 = 0, s4 = 0, s5 = 0, s6 = 0, s7 = 0;
#pragma unroll
    for (int e = 0; e < NEXP; ++e) {
        float4 u0 = *(const float4*)(src + (size_t)e * DIM * DIM);
        float4 u1 = *(const float4*)(src + (size_t)e * DIM * DIM + 4);
        s0 += u0.x; s1 += u0.y; s2 += u0.z; s3 += u0.w;
        s4 += u1.x; s5 += u1.y; s6 += u1.z; s7 += u1.w;
    }
    uint4 v;
    v.x = pk2bf(s0, s1); v.y = pk2bf(s2, s3);
    v.z = pk2bf(s4, s5); v.w = pk2bf(s6, s7);

    const int F  = f >> 6, j = (f >> 4) & 3, lr = f & 15;
    const int sl = q >> 2, lg = q & 3;
    const int idx16 = ((F * 4 + j) * 16 + sl) * 64 + (lg * 16 + lr);
    *(uint4*)(Bfrag + (size_t)idx16 * 8) = v;

    if (g < DIM / 4) {
        float4 bs = make_float4(0.f, 0.f, 0.f, 0.f);
#pragma unroll
        for (int e = 0; e < NEXP; ++e) {
            float4 u = *(const float4*)(b + e * DIM + g * 4);
            bs.x += u.x; bs.y += u.y; bs.z += u.z; bs.w += u.w;
        }
        *(float4*)(bsum + g * 4) = bs;
    }
}

// ---------------- xfrag: x (f32, row-major) -> Afrag (bf16, fragment-major) ----------------
// Block = one 64-token tile. Read coalesced -> convert -> swizzled LDS (proven pair)
// -> barrier -> write 16B/thread fully-coalesced dense chunks.
// Afrag chunk index (16B units): mt*4096 + (s*4 + i)*64 + (lg*16 + lr)
//   holding x_bf16[token = mt*64 + i*16 + lr][k = s*32 + lg*8 + 0..7]  (== R6's sliceA).
__global__ __launch_bounds__(256) void moe_xfrag(const float* __restrict__ x,
                                                 unsigned short* __restrict__ Af) {
    __shared__ __align__(16) unsigned char lds[64 * 1024];   // 64 KB
    const int tid = threadIdx.x;
    const int mt  = blockIdx.x;

    // read phase: thread -> row tid>>2 (0..63), sub c = tid&3; granules g = u*4+c
    // (4 consecutive lanes cover 128B contiguous per u-step).
    {
        const int row = tid >> 2;
        const int c   = tid & 3;
        const float* srcrow = x + ((size_t)mt * 64 + row) * DIM;
        unsigned char* dstrow = lds + row * 1024;
#pragma unroll
        for (int u = 0; u < 16; ++u)
            stage_granule(srcrow, dstrow, u * 4 + c, row);
    }
    __syncthreads();

    // write phase: 4096 chunks of 16B over 256 threads x 16 iters, fully coalesced out.
    {
        unsigned short* dst = Af + (size_t)mt * 4096 * 8;
#pragma unroll
        for (int it = 0; it < 16; ++it) {
            const int o  = it * 256 + tid;
            const int s  = o >> 8;
            const int i  = (o >> 6) & 3;
            const int ln = o & 63;
            const int lr = ln & 15;
            const int lg = ln >> 4;
            const int row = i * 16 + lr;
            const int gsl = s * 4 + lg;
            const int sw  = (gsl & ~7) | ((gsl ^ row) & 7);
            uint4 v = *(const uint4*)(lds + row * 1024 + sw * 16);
            *(uint4*)(dst + (size_t)o * 8) = v;
        }
    }
}

// ---------------- streaming GEMM: LDS-free, barrier-free ----------------
// Wave w of block: wid = blockIdx*4 + w; mt = wid>>3 (token tile), fs = wid&7
// (feature slice). Per slice: 4 dense A-chunk loads (L3-hot) + 4 dense B-chunk
// loads (L2) + 16 MFMA; depth-1 named-reg prefetch on both. Direct stores (proven).
__global__ __launch_bounds__(256) void moe_gemm_s(const float* __restrict__ wts,
                                                  const unsigned short* __restrict__ Bf,
                                                  const unsigned short* __restrict__ Af,
                                                  const float* __restrict__ bsum,
                                                  float* __restrict__ out) {
    const int tid  = threadIdx.x;
    const int lane = tid & 63;
    const int w    = tid >> 6;
    const int wid  = blockIdx.x * 4 + w;
    const int mt   = wid >> 3;
    const int fs   = wid & 7;
    const int lr   = lane & 15;
    const int lg   = lane >> 4;
    const int m0   = mt * 64;
    const int f0   = fs * 64;

    const bf16x8* bfr = (const bf16x8*)Bf + (size_t)fs * 4096 + lane;   // + j*1024 + s*64
    const bf16x8* afr = (const bf16x8*)Af + (size_t)mt * 4096 + lane;   // + (s*4+i)*64

    f32x4 acc[4][4] = {};   // acc[j][i]
    bf16x8 aE[4], aO[4], bE[4], bO[4];

    auto loadB = [&](int s, bf16x8 (&bb)[4]) {
#pragma unroll
        for (int j = 0; j < 4; ++j)
            bb[j] = bfr[j * 1024 + s * 64];
    };
    auto loadA = [&](int s, bf16x8 (&aa)[4]) {
#pragma unroll
        for (int i = 0; i < 4; ++i)
            aa[i] = afr[(s * 4 + i) * 64];
    };
    auto mf = [&](bf16x8 (&bb)[4], bf16x8 (&aa)[4]) {
#pragma unroll
        for (int j = 0; j < 4; ++j)
#pragma unroll
            for (int i = 0; i < 4; ++i)
                acc[j][i] = __builtin_amdgcn_mfma_f32_16x16x32_bf16(bb[j], aa[i], acc[j][i], 0, 0, 0);
    };

    loadB(0, bE); loadA(0, aE);
#pragma unroll
    for (int it = 0; it < 8; ++it) {
        loadB(2 * it + 1, bO); loadA(2 * it + 1, aO);
        mf(bE, aE);
        if (it < 7) { loadB(2 * it + 2, bE); loadA(2 * it + 2, aE); }
        mf(bO, aO);
    }

    // epilogue (proven): token = m0 + i*16 + lr; feats = f0 + j*16 + lg*4
    f32x4 bs4[4];
#pragma unroll
    for (int j = 0; j < 4; ++j)
        bs4[j] = *(const f32x4*)(bsum + f0 + j * 16 + lg * 4);
#pragma unroll
    for (int i = 0; i < 4; ++i) {
        const int row = m0 + i * 16 + lr;
        const float wt = wts[row];
#pragma unroll
        for (int j = 0; j < 4; ++j) {
            f32x4 v;
            v[0] = wt * (acc[j][i][0] + bs4[j][0]);
            v[1] = wt * (acc[j][i][1] + bs4[j][1]);
            v[2] = wt * (acc[j][i][2] + bs4[j][2]);
            v[3] = wt * (acc[j][i][3] + bs4[j][3]);
            *(f32x4*)(out + (size_t)row * DIM + f0 + j * 16 + lg * 4) = v;
        }
    }
}

// ---------------- fallback fused GEMM (R6-proven, 44.2us) ----------------
__global__ __launch_bounds__(512, 4) void moe_gemm_fused(const float* __restrict__ x,
                                                         const float* __restrict__ wts,
                                                         const unsigned short* __restrict__ Bf,
                                                         const float* __restrict__ bsum,
                                                         float* __restrict__ out) {
    __shared__ __align__(16) unsigned char ldsA[64 * DIM * 2];   // 64 KB
    const int tid  = threadIdx.x;
    const int lane = tid & 63;
    const int w    = tid >> 6;
    const int lr   = lane & 15;
    const int lg   = lane >> 4;
    const int m0   = blockIdx.x * 64;
    const int f0   = w * 64;
    {
        const int row = tid >> 3;
        const int s0  = tid & 7;
        const float* srcrow = x + (size_t)(m0 + row) * DIM;
        unsigned char* dstrow = ldsA + row * 1024;
#pragma unroll
        for (int i = 0; i < 8; ++i)
            stage_granule(srcrow, dstrow, s0 + i * 8, row);
    }
    __syncthreads();
    const bf16x8* bfr = (const bf16x8*)Bf + (size_t)w * 4096 + lane;
    f32x4 acc[4][4] = {};
    bf16x8 bE[4], bO[4], af[4];
    auto loadB = [&](int s, bf16x8 (&bb)[4]) {
#pragma unroll
        for (int j = 0; j < 4; ++j) bb[j] = bfr[j * 1024 + s * 64];
    };
    auto sliceA = [&](int s) {
#pragma unroll
        for (int i = 0; i < 4; ++i) {
            const int row = i * 16 + lr;
            const int gsl = s * 4 + lg;
            const int sw  = (gsl & ~7) | ((gsl ^ row) & 7);
            af[i] = *(const bf16x8*)(ldsA + row * 1024 + sw * 16);
        }
    };
    auto mf = [&](bf16x8 (&bb)[4]) {
#pragma unroll
        for (int j = 0; j < 4; ++j)
#pragma unroll
            for (int i = 0; i < 4; ++i)
                acc[j][i] = __builtin_amdgcn_mfma_f32_16x16x32_bf16(bb[j], af[i], acc[j][i], 0, 0, 0);
    };
    loadB(0, bE);
#pragma unroll
    for (int it = 0; it < 8; ++it) {
        loadB(2 * it + 1, bO); sliceA(2 * it); mf(bE);
        if (it < 7) loadB(2 * it + 2, bE);
        sliceA(2 * it + 1); mf(bO);
    }
    f32x4 bs4[4];
#pragma unroll
    for (int j = 0; j < 4; ++j) bs4[j] = *(const f32x4*)(bsum + f0 + j * 16 + lg * 4);
#pragma unroll
    for (int i = 0; i < 4; ++i) {
        const int row = m0 + i * 16 + lr;
        const float wt = wts[row];
#pragma unroll
        for (int j = 0; j < 4; ++j) {
            f32x4 v;
            v[0] = wt * (acc[j][i][0] + bs4[j][0]);
            v[1] = wt * (acc[j][i][1] + bs4[j][1]);
            v[2] = wt * (acc[j][i][2] + bs4[j][2]);
            v[3] = wt * (acc[j][i][3] + bs4[j][3]);
            *(f32x4*)(out + (size_t)row * DIM + f0 + j * 16 + lg * 4) = v;
        }
    }
}

extern "C" void kernel_launch(void* const* d_in, const int* in_sizes, int n_in,
                              void* d_out, int out_size, void* d_ws, size_t ws_size,
                              hipStream_t stream) {
    const float* x   = (const float*)d_in[0];   // [N, D]
    const float* wts = (const float*)d_in[1];   // [N, 1]
    const float* W   = (const float*)d_in[2];   // [E, D, D]
    const float* b   = (const float*)d_in[3];   // [E, D]
    float* out       = (float*)d_out;           // [N, D]

    unsigned short* Bfrag = (unsigned short*)d_ws;                    // 512 KB bf16
    float*          bsum  = (float*)((char*)d_ws + DIM * DIM * 2);    // 2 KB f32
    unsigned short* Afrag = (unsigned short*)((char*)d_ws + (1u << 20));  // 32 MB bf16

    const size_t need = (1u << 20) + (size_t)N_TOK * DIM * 2;

    moe_prep<<<dim3((DIM * DIM / 8) / 64), dim3(64), 0, stream>>>(W, b, Bfrag, bsum);

    if (ws_size >= need) {
        moe_xfrag<<<dim3(N_TOK / 64), dim3(256), 0, stream>>>(x, Afrag);
        moe_gemm_s<<<dim3((N_TOK / 64) * (DIM / 64) / 4), dim3(256), 0, stream>>>(
            wts, Bfrag, Afrag, bsum, out);
    } else {
        moe_gemm_fused<<<dim3(N_TOK / 64), dim3(512), 0, stream>>>(x, wts, Bfrag, bsum, out);
    }
}

// Round 17
// 40.717 us; speedup vs baseline: 1.4878x; 1.4878x over previous
//
#include <hip/hip_runtime.h>
#include <hip/hip_bf16.h>

// out[n,f] = weights[n] * ( x[n,:] . Wsum[f,:] + bsum[f] )
// Wsum = sum_e W[e], bsum = sum_e b[e]  (expert sum commutes with Linear).
// Wsum stored fragment-major ("Bfrag", R6) -> dense lane-consecutive B streams.
// R11/R13 champion: producer-consumer wave specialization (8 compute + 4 stager
// waves), 2 tiles/block, all-wave front stage, LDS dbuf.
// R16: depth-3 B prefetch -- named sets b0/b1/b2, slice s uses b[s%3] and reloads
// slice s+3 into the same set right after the MFMA cluster, pinned per-slice with
// sched_barrier(0) (R10 proved the compiler sinks unpinned prefetch to depth-0;
// R9 proved sched_barrier pinning holds). Cover: ~2 slices of MFMA >= L2 latency.

#define N_TOK 32768
#define DIM   512
#define NEXP  8
#define BM    64            // tokens per tile
#define TILES 2             // tiles per block

typedef __attribute__((ext_vector_type(8))) short  bf16x8;
typedef __attribute__((ext_vector_type(4))) float  f32x4;

__device__ __forceinline__ unsigned int pk2bf(float a, float b) {
    unsigned ua = __float_as_uint(a), ub = __float_as_uint(b);
    ua = (ua + 0x7FFFu + ((ua >> 16) & 1u)) >> 16;   // RNE to bf16
    ub = (ub + 0x7FFFu + ((ub >> 16) & 1u)) >> 16;
    return ua | (ub << 16);
}

// ---------------- prep: Bfrag (bf16, fragment-major) + bsum (f32) ---- (proven) ----
__global__ __launch_bounds__(64) void moe_prep(const float* __restrict__ W,
                                               const float* __restrict__ b,
                                               unsigned short* __restrict__ Bfrag,
                                               float* __restrict__ bsum) {
    const int g = blockIdx.x * 64 + threadIdx.x;     // 0..32767
    const int f = g >> 6;
    const int q = g & 63;
    const float* src = W + (size_t)f * DIM + q * 8;
    float s0 = 0, s1 = 0, s2 = 0, s3 = 0, s4 = 0, s5 = 0, s6 = 0, s7 = 0;
#pragma unroll
    for (int e = 0; e < NEXP; ++e) {
        float4 u0 = *(const float4*)(src + (size_t)e * DIM * DIM);
        float4 u1 = *(const float4*)(src + (size_t)e * DIM * DIM + 4);
        s0 += u0.x; s1 += u0.y; s2 += u0.z; s3 += u0.w;
        s4 += u1.x; s5 += u1.y; s6 += u1.z; s7 += u1.w;
    }
    uint4 v;
    v.x = pk2bf(s0, s1); v.y = pk2bf(s2, s3);
    v.z = pk2bf(s4, s5); v.w = pk2bf(s6, s7);

    const int F  = f >> 6, j = (f >> 4) & 3, lr = f & 15;
    const int sl = q >> 2, lg = q & 3;
    const int idx16 = ((F * 4 + j) * 16 + sl) * 64 + (lg * 16 + lr);
    *(uint4*)(Bfrag + (size_t)idx16 * 8) = v;

    if (g < DIM / 4) {
        float4 bs = make_float4(0.f, 0.f, 0.f, 0.f);
#pragma unroll
        for (int e = 0; e < NEXP; ++e) {
            float4 u = *(const float4*)(b + e * DIM + g * 4);
            bs.x += u.x; bs.y += u.y; bs.z += u.z; bs.w += u.w;
        }
        *(float4*)(bsum + g * 4) = bs;
    }
}

// ---- one granule: 8 f32 -> 16B bf16, XOR-swizzled LDS write (proven pair) ----
__device__ __forceinline__ void stage_granule(const float* __restrict__ srcrow,
                                              unsigned char* __restrict__ dstrow,
                                              int g, int row) {
    float4 u0 = *(const float4*)(srcrow + g * 8);
    float4 u1 = *(const float4*)(srcrow + g * 8 + 4);
    const int sg = (g & ~7) | ((g ^ row) & 7);
    uint4 v;
    v.x = pk2bf(u0.x, u0.y); v.y = pk2bf(u0.z, u0.w);
    v.z = pk2bf(u1.x, u1.y); v.w = pk2bf(u1.z, u1.w);
    *(uint4*)(dstrow + sg * 16) = v;
}

// ---------------- main GEMM: producer-consumer, 2 tiles, depth-3 B prefetch ----------------
// Grid 256 (1 block/CU via 128KB LDS). Block = 12 waves: w0-7 compute (wave w owns
// features [w*64,(w+1)*64) of 64 tokens), w8-11 stage tile1 during kloop(0).
__global__ __launch_bounds__(768) void moe_gemm(const float* __restrict__ x,
                                                const float* __restrict__ wts,
                                                const unsigned short* __restrict__ Bf,
                                                const float* __restrict__ bsum,
                                                float* __restrict__ out) {
    __shared__ __align__(16) unsigned char ldsA[2][BM * DIM * 2];   // 2 x 64 KB

    const int tid  = threadIdx.x;
    const int lane = tid & 63;
    const int w    = tid >> 6;       // 0..11
    const bool stager = (w >= 8);
    const int lr   = lane & 15;
    const int lg   = lane >> 4;
    const int blk  = blockIdx.x;
    const int f0   = w * 64;         // compute waves only

    // ---- front: stage tile0 with ALL 12 waves (R13-proven). 64x64 granules.
    {
        const float* src0 = x + (size_t)(blk * TILES) * BM * DIM;
#pragma unroll
        for (int u = 0; u < 6; ++u) {
            const int gl = u * 768 + tid;
            if (gl < 64 * 64) {
                const int row = gl >> 6;
                const int g   = gl & 63;
                stage_granule(src0 + (size_t)row * DIM, ldsA[0] + row * 1024, g, row);
            }
        }
    }
    __syncthreads();                  // bar1: buf0 ready

    // ---- stager geometry for tile1 (R11-proven): st=tid-512 -> row st>>2, slot st&3
    const int st   = tid - 512;
    const int arow = (st >> 2) & 63;
    const int as0  = st & 3;

    // ---- compute lambdas
    const bf16x8* bfr = (const bf16x8*)Bf + (size_t)w * 4096 + lane;   // + j*1024 + s*64

    f32x4 acc[4][4];
    bf16x8 b0[4], b1[4], b2[4], af[4];

    auto loadB = [&](int s, bf16x8 (&bb)[4]) {
#pragma unroll
        for (int j = 0; j < 4; ++j)
            bb[j] = bfr[j * 1024 + s * 64];
    };
    auto sliceA = [&](int buf, int s) {
#pragma unroll
        for (int i = 0; i < 4; ++i) {
            const int row = i * 16 + lr;
            const int gsl = s * 4 + lg;
            const int sw  = (gsl & ~7) | ((gsl ^ row) & 7);
            af[i] = *(const bf16x8*)(ldsA[buf] + row * 1024 + sw * 16);
        }
    };
    auto mf = [&](bf16x8 (&bb)[4]) {
#pragma unroll
        for (int j = 0; j < 4; ++j)
#pragma unroll
            for (int i = 0; i < 4; ++i)
                acc[j][i] = __builtin_amdgcn_mfma_f32_16x16x32_bf16(bb[j], af[i], acc[j][i], 0, 0, 0);
    };
    // depth-3 rotation: slice s uses b[s%3]; after its MFMAs, reload slice s+3
    // into the same set; sched_barrier(0) pins the load at this program point.
    auto kloop = [&](int buf) {
#pragma unroll
        for (int j = 0; j < 4; ++j)
#pragma unroll
            for (int i = 0; i < 4; ++i)
                acc[j][i] = f32x4{0.f, 0.f, 0.f, 0.f};
        loadB(0, b0); loadB(1, b1); loadB(2, b2);
#define KSTEP(s, BSET)                                        \
        { sliceA(buf, s); mf(BSET);                           \
          if ((s) + 3 < 16) loadB((s) + 3, BSET);             \
          __builtin_amdgcn_sched_barrier(0); }
        KSTEP(0,  b0) KSTEP(1,  b1) KSTEP(2,  b2)
        KSTEP(3,  b0) KSTEP(4,  b1) KSTEP(5,  b2)
        KSTEP(6,  b0) KSTEP(7,  b1) KSTEP(8,  b2)
        KSTEP(9,  b0) KSTEP(10, b1) KSTEP(11, b2)
        KSTEP(12, b0) KSTEP(13, b1) KSTEP(14, b2)
        KSTEP(15, b0)
#undef KSTEP
    };
    auto epilogue = [&](int tile) {
        const int m0 = (blk * TILES + tile) * BM;
        f32x4 bs4[4];
#pragma unroll
        for (int j = 0; j < 4; ++j)
            bs4[j] = *(const f32x4*)(bsum + f0 + j * 16 + lg * 4);
#pragma unroll
        for (int i = 0; i < 4; ++i) {
            const int row = m0 + i * 16 + lr;
            const float wt = wts[row];
#pragma unroll
            for (int j = 0; j < 4; ++j) {
                f32x4 v;
                v[0] = wt * (acc[j][i][0] + bs4[j][0]);
                v[1] = wt * (acc[j][i][1] + bs4[j][1]);
                v[2] = wt * (acc[j][i][2] + bs4[j][2]);
                v[3] = wt * (acc[j][i][3] + bs4[j][3]);
                *(f32x4*)(out + (size_t)row * DIM + f0 + j * 16 + lg * 4) = v;
            }
        }
    };

    // ================= schedule (R11-proven) =================
    if (stager) {
        // stage tile1 WHILE compute runs tile0
        const float* srcrow = x + (size_t)((blk * TILES + 1) * BM + arow) * DIM;
        unsigned char* dstrow = ldsA[1] + arow * 1024;
#pragma unroll
        for (int u = 0; u < 16; ++u)
            stage_granule(srcrow, dstrow, as0 + u * 4, arow);
    } else {
        kloop(0);                     // tile0 compute (A from buf0, B from L2)
    }
    __syncthreads();                  // bar2: buf1 ready

    if (!stager) {
        epilogue(0);                  // tile0 stores issue; drain under tile1 kloop
        kloop(1);                     // tile1 compute
        epilogue(1);                  // tail drain
    }
}

extern "C" void kernel_launch(void* const* d_in, const int* in_sizes, int n_in,
                              void* d_out, int out_size, void* d_ws, size_t ws_size,
                              hipStream_t stream) {
    const float* x   = (const float*)d_in[0];   // [N, D]
    const float* wts = (const float*)d_in[1];   // [N, 1]
    const float* W   = (const float*)d_in[2];   // [E, D, D]
    const float* b   = (const float*)d_in[3];   // [E, D]
    float* out       = (float*)d_out;           // [N, D]

    unsigned short* Bfrag = (unsigned short*)d_ws;                    // 512 KB bf16
    float*          bsum  = (float*)((char*)d_ws + DIM * DIM * 2);    // 2 KB f32

    moe_prep<<<dim3((DIM * DIM / 8) / 64), dim3(64), 0, stream>>>(W, b, Bfrag, bsum);

    moe_gemm<<<dim3(N_TOK / (BM * TILES)), dim3(768), 0, stream>>>(x, wts, Bfrag, bsum, out);
}